// Round 9
// baseline (217.180 us; speedup 1.0000x reference)
//
#include <hip/hip_runtime.h>
#include <stdint.h>

typedef __attribute__((ext_vector_type(2))) float f32x2;
typedef __attribute__((ext_vector_type(4))) float f32x4;
typedef __attribute__((ext_vector_type(8))) short bf16x8;

static constexpr int N_ = 4, C_ = 256, HW_ = 4096;
static constexpr int CO_ = 256, KTAP = 9, KK = 2304;  // KK = C_*KTAP
static constexpr int NSTEP = 72;                      // K-steps of 32
static constexpr int A_PLANE = 16 * 64 * 16;          // one BK=32 plane of A: 16KB

static constexpr size_t NHWC_BYTES = (size_t)N_ * HW_ * C_ * 2;  // 8 MB
static constexpr size_t ABF_OFF    = NHWC_BYTES;
static constexpr size_t ABF_BYTES  = (size_t)NSTEP * A_PLANE;    // 1.18 MB

__device__ inline unsigned f2bf(float f) {
  unsigned u = __builtin_bit_cast(unsigned, f);
  unsigned r = u + 0x7FFFu + ((u >> 16) & 1u);
  return r >> 16;
}
__device__ inline float asf(unsigned u) { return __builtin_bit_cast(float, u); }

// ---------------- merged prep: NCHW->NHWC bf16 (blocks 0..1023) +
//                  filter -> fragment-major bf16 (blocks 1024..1279) ----------
__global__ __launch_bounds__(256) void k_prep(const float* __restrict__ in,
                                              const float* __restrict__ filt,
                                              unsigned short* __restrict__ nhwc,
                                              unsigned short* __restrict__ abf2) {
  int b = blockIdx.x;
  int t = threadIdx.x;
  if (b < 1024) {
    __shared__ float tile[64][65];
    int n = b >> 8, cg = (b >> 6) & 3, hwg = b & 63;
    int c0 = cg * 64, hw0 = hwg * 64;
    int col = t & 63, r0 = t >> 6;
#pragma unroll
    for (int i = 0; i < 16; ++i) {
      int row = r0 + i * 4;
      tile[row][col] = in[(size_t)(n * C_ + c0 + row) * HW_ + hw0 + col];
    }
    __syncthreads();
    int pr = t >> 2, cc0 = (t & 3) * 16;
    unsigned us[8];
#pragma unroll
    for (int i = 0; i < 8; ++i) {
      unsigned lo = f2bf(tile[cc0 + 2 * i][pr]);
      unsigned hi = f2bf(tile[cc0 + 2 * i + 1][pr]);
      us[i] = lo | (hi << 16);
    }
    unsigned* dst = (unsigned*)(nhwc + (size_t)(n * HW_ + hw0 + pr) * C_ + c0 + cc0);
    ((uint4*)dst)[0] = make_uint4(us[0], us[1], us[2], us[3]);
    ((uint4*)dst)[1] = make_uint4(us[4], us[5], us[6], us[7]);
  } else {
    int gid = (b - 1024) * 256 + t;
    int o = gid >> 8, c = gid & 255;
    const float* f = filt + (size_t)(o * C_ + c) * KTAP;
    int rb = o >> 4;
    int lane = ((c >> 3) & 3) * 16 + (o & 15);
    int j = c & 7;
#pragma unroll
    for (int tap = 0; tap < KTAP; ++tap) {
      int s = tap * 8 + (c >> 5);
      abf2[((size_t)(s * 16 + rb) * 64 + lane) * 8 + j] = (unsigned short)f2bf(f[tap]);
    }
  }
}

struct GB { uint4 g[4]; f32x4 w; };

__device__ __forceinline__ f32x2 unpk(unsigned u) {
  return (f32x2){asf(u << 16), asf(u & 0xffff0000u)};
}

// bilinear combine: 8 channels (one uint4 per corner) -> 16B into LDS
__device__ __forceinline__ void buildB8(const GB& b, char* dst) {
  f32x2 r0 = b.w.x * unpk(b.g[0].x) + b.w.y * unpk(b.g[1].x) +
             b.w.z * unpk(b.g[2].x) + b.w.w * unpk(b.g[3].x);
  f32x2 r1 = b.w.x * unpk(b.g[0].y) + b.w.y * unpk(b.g[1].y) +
             b.w.z * unpk(b.g[2].y) + b.w.w * unpk(b.g[3].y);
  f32x2 r2 = b.w.x * unpk(b.g[0].z) + b.w.y * unpk(b.g[1].z) +
             b.w.z * unpk(b.g[2].z) + b.w.w * unpk(b.g[3].z);
  f32x2 r3 = b.w.x * unpk(b.g[0].w) + b.w.y * unpk(b.g[1].w) +
             b.w.z * unpk(b.g[2].w) + b.w.w * unpk(b.g[3].w);
  unsigned o0, o1, o2, o3;
  asm("v_cvt_pk_bf16_f32 %0, %1, %2" : "=v"(o0) : "v"(r0.x), "v"(r0.y));
  asm("v_cvt_pk_bf16_f32 %0, %1, %2" : "=v"(o1) : "v"(r1.x), "v"(r1.y));
  asm("v_cvt_pk_bf16_f32 %0, %1, %2" : "=v"(o2) : "v"(r2.x), "v"(r2.y));
  asm("v_cvt_pk_bf16_f32 %0, %1, %2" : "=v"(o3) : "v"(r3.x), "v"(r3.y));
  *(uint4*)dst = make_uint4(o0, o1, o2, o3);
}

#define MFMA_BF16 __builtin_amdgcn_mfma_f32_16x16x32_bf16

// One K-step, role-split, ablation-gated by MODE.
#define PIPE(S, RDP, WRP, GCON, GISS, AC0, AC1, AN0, AN1)                      \
  do {                                                                         \
    if (cons) {                                                                \
      const char* a0_;                                                         \
      if constexpr (MODE == 4) {                                               \
        a0_ = aoff0 + (((S) & 1) << 4);  /* L1-pinned A */                     \
      } else {                                                                 \
        int s1_ = (S) + 1 < NSTEP ? (S) + 1 : NSTEP - 1;                       \
        a0_ = aoff0 + (size_t)s1_ * A_PLANE;                                   \
      }                                                                        \
      AN0 = *(const bf16x8*)(a0_);                                             \
      AN1 = *(const bf16x8*)(a0_ + 1024);                                      \
      bf16x8 b0_, b1_, b2_, b3_;                                               \
      if constexpr (MODE == 3) {                                               \
        b0_ = AC0; b1_ = AC1; b2_ = AC0; b3_ = AC1;  /* no B ds_read */        \
      } else {                                                                 \
        const char* bb_ = (const char*)&Bl[0][0] + (RDP) * 4096;               \
        b0_ = *(const bf16x8*)(bb_ + bo0);                                     \
        b1_ = *(const bf16x8*)(bb_ + bo1);                                     \
        b2_ = *(const bf16x8*)(bb_ + bo2);                                     \
        b3_ = *(const bf16x8*)(bb_ + bo3);                                     \
      }                                                                        \
      __builtin_amdgcn_s_setprio(1);                                           \
      acc[0][0] = MFMA_BF16(AC0, b0_, acc[0][0], 0, 0, 0);                     \
      acc[1][0] = MFMA_BF16(AC1, b0_, acc[1][0], 0, 0, 0);                     \
      acc[0][1] = MFMA_BF16(AC0, b1_, acc[0][1], 0, 0, 0);                     \
      acc[1][1] = MFMA_BF16(AC1, b1_, acc[1][1], 0, 0, 0);                     \
      __builtin_amdgcn_s_setprio(0);                                           \
      __builtin_amdgcn_s_setprio(1);                                           \
      acc[0][2] = MFMA_BF16(AC0, b2_, acc[0][2], 0, 0, 0);                     \
      acc[1][2] = MFMA_BF16(AC1, b2_, acc[1][2], 0, 0, 0);                     \
      acc[0][3] = MFMA_BF16(AC0, b3_, acc[0][3], 0, 0, 0);                     \
      acc[1][3] = MFMA_BF16(AC1, b3_, acc[1][3], 0, 0, 0);                     \
      __builtin_amdgcn_s_setprio(0);                                           \
    } else {                                                                   \
      if constexpr (MODE == 1) {                                               \
        /* gathers pinned to the tap-0 lines: same rows, tiny offset jitter */ \
        unsigned co_ = (unsigned)(((S) & 3) << 4);                             \
        GISS.g[0] = *(const uint4*)(nb_u + vS.x + co_);                        \
        GISS.g[1] = *(const uint4*)(nb_u + vS.y + co_);                        \
        GISS.g[2] = *(const uint4*)(nb_u + vS.z + co_);                        \
        GISS.g[3] = *(const uint4*)(nb_u + vS.w + co_);                        \
        GISS.w = wS;                                                           \
      } else {                                                                 \
        int s2_ = (S) + 2 < NSTEP ? (S) + 2 : NSTEP - 1;                       \
        if ((s2_ & 7) == 0) {                                                  \
          int tp_ = s2_ >> 3;                                                  \
          uint4 ra_ = *(const uint4*)&recA[(tp_ * 64 + p_b) * 4];              \
          wS = *(const f32x4*)&recW[(tp_ * 64 + p_b) * 4];                     \
          vS.x = ra_.x + kq16; vS.y = ra_.y + kq16;                            \
          vS.z = ra_.z + kq16; vS.w = ra_.w + kq16;                            \
        }                                                                      \
        unsigned co_ = (unsigned)((s2_ & 7) * 64);                             \
        GISS.g[0] = *(const uint4*)(nb_u + vS.x + co_);                        \
        GISS.g[1] = *(const uint4*)(nb_u + vS.y + co_);                        \
        GISS.g[2] = *(const uint4*)(nb_u + vS.z + co_);                        \
        GISS.g[3] = *(const uint4*)(nb_u + vS.w + co_);                        \
        GISS.w = wS;                                                           \
      }                                                                        \
      if constexpr (MODE == 2) {                                               \
        /* no build / ds_write / drain; keep loads live */                     \
        asm volatile("" :: "v"(GISS.g[0].x), "v"(GISS.g[1].x),                 \
                     "v"(GISS.g[2].x), "v"(GISS.g[3].x), "v"(GCON.g[0].x));    \
      } else {                                                                 \
        buildB8(GCON, bwp + (WRP) * 4096);                                     \
        asm volatile("s_waitcnt lgkmcnt(0)" ::: "memory");                     \
      }                                                                        \
    }                                                                          \
    asm volatile("" ::: "memory");                                             \
    __builtin_amdgcn_s_barrier();                                              \
    asm volatile("" ::: "memory");                                             \
  } while (0)

// ---------------- fused sample + GEMM (producer/consumer waves) ----------------
// 256 blocks x 768 threads (12 waves): waves 0-7 consumers (32 Cout x 64 px),
// waves 8-11 producers (64 px x 4 kq x 8ch). B buffers: 2 x 4KB, parity stride
// 4096 (round-6 race FIXED). Plane p=ch>>3: addr = p*1024 + ((px+5p)&63)*16.
template <int MODE>
__global__ __launch_bounds__(768, 3) void k_dcn_gemm_t(const unsigned short* __restrict__ nhwc,
                                                       const unsigned short* __restrict__ abf2,
                                                       const float* __restrict__ offs,
                                                       const float* __restrict__ msk,
                                                       float* __restrict__ out) {
  __shared__ __align__(16) unsigned short Bl[2][2048];  // 2 x 4KB step buffers
  __shared__ float recW[KTAP * 64 * 4];
  __shared__ unsigned recA[KTAP * 64 * 4];

  int bid = blockIdx.x;
  int b = ((bid & 7) << 5) | (bid >> 3);  // XCD-aware swizzle
  int n = b >> 6;
  int ho = b & 63;
  int hw0 = ho << 6;
  int t = threadIdx.x;

  for (int r = t; r < 576; r += 768) {
    int pl = r / 9;
    int tap = r - pl * 9;
    int hw = hw0 + pl;
    float dy = offs[(size_t)(n * 18 + 2 * tap) * HW_ + hw];
    float dx = offs[(size_t)(n * 18 + 2 * tap + 1) * HW_ + hw];
    float mk = msk[(size_t)(n * 9 + tap) * HW_ + hw];
    float y = (float)(ho - 1 + tap / 3) + dy;
    float x = (float)(pl - 1 + tap % 3) + dx;
    float fy = floorf(y), fx = floorf(x);
    float ly = y - fy, lx = x - fx;
    int y0 = (int)fy, x0 = (int)fx;
    int y1 = y0 + 1, x1 = x0 + 1;
    float vy0 = (y0 >= 0 && y0 < 64) ? 1.f : 0.f;
    float vy1 = (y1 >= 0 && y1 < 64) ? 1.f : 0.f;
    float vx0 = (x0 >= 0 && x0 < 64) ? 1.f : 0.f;
    float vx1 = (x1 >= 0 && x1 < 64) ? 1.f : 0.f;
    int y0c = min(max(y0, 0), 63), y1c = min(max(y1, 0), 63);
    int x0c = min(max(x0, 0), 63), x1c = min(max(x1, 0), 63);
    int base = (tap * 64 + pl) * 4;
    recW[base + 0] = (1.f - ly) * (1.f - lx) * mk * vy0 * vx0;
    recW[base + 1] = (1.f - ly) * lx * mk * vy0 * vx1;
    recW[base + 2] = ly * (1.f - lx) * mk * vy1 * vx0;
    recW[base + 3] = ly * lx * mk * vy1 * vx1;
    recA[base + 0] = (unsigned)((y0c * 64 + x0c) * 512);
    recA[base + 1] = (unsigned)((y0c * 64 + x1c) * 512);
    recA[base + 2] = (unsigned)((y1c * 64 + x0c) * 512);
    recA[base + 3] = (unsigned)((y1c * 64 + x1c) * 512);
  }
  __syncthreads();

  int lane = t & 63, wv = t >> 6;
  bool cons = wv < 8;

  const char* aoff0 = (const char*)abf2 + ((wv * 2 + 0) * 64 + lane) * 16;
  int p_r = lane >> 4;
  int pxl = lane & 15;
  const int bo0 = p_r * 1024 + (((pxl + 0) + 5 * p_r) & 63) * 16;
  const int bo1 = p_r * 1024 + (((pxl + 16) + 5 * p_r) & 63) * 16;
  const int bo2 = p_r * 1024 + (((pxl + 32) + 5 * p_r) & 63) * 16;
  const int bo3 = p_r * 1024 + (((pxl + 48) + 5 * p_r) & 63) * 16;

  int pid = t - 512;
  int p_b = (pid >> 2) & 63;
  int kq = pid & 3;
  unsigned kq16 = (unsigned)(kq * 16);
  const char* nb_u = (const char*)nhwc + (size_t)n * HW_ * C_ * 2;
  char* bwp = (char*)&Bl[0][0] + kq * 1024 + ((p_b + 5 * kq) & 63) * 16;

  f32x4 acc[2][4];
#pragma unroll
  for (int mi = 0; mi < 2; ++mi)
#pragma unroll
    for (int ni = 0; ni < 4; ++ni) acc[mi][ni] = (f32x4){0.f, 0.f, 0.f, 0.f};

  GB gA, gB;
  bf16x8 afc0, afc1, afn0, afn1;
  uint4 vS;
  f32x4 wS;

  if (cons) {
    afc0 = *(const bf16x8*)(aoff0);
    afc1 = *(const bf16x8*)(aoff0 + 1024);
  } else {
    uint4 ra0 = *(const uint4*)&recA[p_b * 4];  // tap 0
    wS = *(const f32x4*)&recW[p_b * 4];
    vS.x = ra0.x + kq16; vS.y = ra0.y + kq16;
    vS.z = ra0.z + kq16; vS.w = ra0.w + kq16;
    gA.g[0] = *(const uint4*)(nb_u + vS.x);
    gA.g[1] = *(const uint4*)(nb_u + vS.y);
    gA.g[2] = *(const uint4*)(nb_u + vS.z);
    gA.g[3] = *(const uint4*)(nb_u + vS.w);
    gA.w = wS;
    gB.g[0] = *(const uint4*)(nb_u + vS.x + 64);
    gB.g[1] = *(const uint4*)(nb_u + vS.y + 64);
    gB.g[2] = *(const uint4*)(nb_u + vS.z + 64);
    gB.g[3] = *(const uint4*)(nb_u + vS.w + 64);
    gB.w = wS;
    buildB8(gA, bwp);  // B(0) into buf0
    asm volatile("s_waitcnt lgkmcnt(0)" ::: "memory");
  }
  asm volatile("" ::: "memory");
  __builtin_amdgcn_s_barrier();
  asm volatile("" ::: "memory");

  for (int s = 0; s < NSTEP; s += 2) {
    PIPE(s,     0, 1, gB, gA, afc0, afc1, afn0, afn1);
    PIPE(s + 1, 1, 0, gA, gB, afn0, afn1, afc0, afc1);
  }

  if (cons) {
    float* ob = out + (size_t)n * CO_ * HW_ + hw0;
#pragma unroll
    for (int mi = 0; mi < 2; ++mi)
#pragma unroll
      for (int ni = 0; ni < 4; ++ni)
#pragma unroll
        for (int jj = 0; jj < 4; ++jj) {
          int o = wv * 32 + mi * 16 + (lane >> 4) * 4 + jj;
          int hw = ni * 16 + (lane & 15);
          ob[(size_t)o * HW_ + hw] = acc[mi][ni][jj];
        }
  }
}

extern "C" void kernel_launch(void* const* d_in, const int* in_sizes, int n_in,
                              void* d_out, int out_size, void* d_ws, size_t ws_size,
                              hipStream_t stream) {
  const float* inp  = (const float*)d_in[0];
  const float* filt = (const float*)d_in[1];
  const float* offs = (const float*)d_in[2];
  const float* msk  = (const float*)d_in[3];
  float* out = (float*)d_out;
  if (ws_size < ABF_OFF + ABF_BYTES) return;  // ~9.6 MB scratch
  unsigned short* nhwc = (unsigned short*)d_ws;
  unsigned short* abf2 = (unsigned short*)((char*)d_ws + ABF_OFF);

  k_prep<<<1280, 256, 0, stream>>>(inp, filt, nhwc, abf2);
  // diagnostics (write garbage to d_out; real kernel below overwrites fully)
  k_dcn_gemm_t<1><<<256, 768, 0, stream>>>(nhwc, abf2, offs, msk, out);
  k_dcn_gemm_t<2><<<256, 768, 0, stream>>>(nhwc, abf2, offs, msk, out);
  k_dcn_gemm_t<3><<<256, 768, 0, stream>>>(nhwc, abf2, offs, msk, out);
  k_dcn_gemm_t<4><<<256, 768, 0, stream>>>(nhwc, abf2, offs, msk, out);
  // real kernel LAST
  k_dcn_gemm_t<0><<<256, 768, 0, stream>>>(nhwc, abf2, offs, msk, out);
}

// Round 10
// 74.430 us; speedup vs baseline: 2.9179x; 2.9179x over previous
//
#include <hip/hip_runtime.h>
#include <stdint.h>

typedef __attribute__((ext_vector_type(2))) float f32x2;
typedef __attribute__((ext_vector_type(4))) float f32x4;
typedef __attribute__((ext_vector_type(8))) short bf16x8;

static constexpr int N_ = 4, C_ = 256, HW_ = 4096;
static constexpr int CO_ = 256, KTAP = 9, KK = 2304;  // KK = C_*KTAP
static constexpr int NPH = 18;                        // phases of 4 K-steps (BK=32)
static constexpr int A_PLANE = 16 * 64 * 16;          // one BK=32 plane of A: 16KB

static constexpr size_t NHWC_BYTES = (size_t)N_ * HW_ * C_ * 2;  // 8 MB
static constexpr size_t ABF_OFF    = NHWC_BYTES;
static constexpr size_t ABF_BYTES  = (size_t)72 * A_PLANE;       // 1.18 MB

__device__ inline unsigned f2bf(float f) {
  unsigned u = __builtin_bit_cast(unsigned, f);
  unsigned r = u + 0x7FFFu + ((u >> 16) & 1u);
  return r >> 16;
}
__device__ inline float asf(unsigned u) { return __builtin_bit_cast(float, u); }

// ---------------- merged prep: NCHW->NHWC bf16 (blocks 0..1023) +
//                  filter -> fragment-major bf16 (blocks 1024..1279) ----------
__global__ __launch_bounds__(256) void k_prep(const float* __restrict__ in,
                                              const float* __restrict__ filt,
                                              unsigned short* __restrict__ nhwc,
                                              unsigned short* __restrict__ abf2) {
  int b = blockIdx.x;
  int t = threadIdx.x;
  if (b < 1024) {
    __shared__ float tile[64][65];
    int n = b >> 8, cg = (b >> 6) & 3, hwg = b & 63;
    int c0 = cg * 64, hw0 = hwg * 64;
    int col = t & 63, r0 = t >> 6;
#pragma unroll
    for (int i = 0; i < 16; ++i) {
      int row = r0 + i * 4;
      tile[row][col] = in[(size_t)(n * C_ + c0 + row) * HW_ + hw0 + col];
    }
    __syncthreads();
    int pr = t >> 2, cc0 = (t & 3) * 16;
    unsigned us[8];
#pragma unroll
    for (int i = 0; i < 8; ++i) {
      unsigned lo = f2bf(tile[cc0 + 2 * i][pr]);
      unsigned hi = f2bf(tile[cc0 + 2 * i + 1][pr]);
      us[i] = lo | (hi << 16);
    }
    unsigned* dst = (unsigned*)(nhwc + (size_t)(n * HW_ + hw0 + pr) * C_ + c0 + cc0);
    ((uint4*)dst)[0] = make_uint4(us[0], us[1], us[2], us[3]);
    ((uint4*)dst)[1] = make_uint4(us[4], us[5], us[6], us[7]);
  } else {
    // abf2[((s*16 + rb)*64 + lane)*8 + j]: s = tap*8+(c>>5), rb=o>>4,
    // lane = ((c>>3)&3)*16 + (o&15), j = c&7.
    int gid = (b - 1024) * 256 + t;
    int o = gid >> 8, c = gid & 255;
    const float* f = filt + (size_t)(o * C_ + c) * KTAP;
    int rb = o >> 4;
    int lane = ((c >> 3) & 3) * 16 + (o & 15);
    int j = c & 7;
#pragma unroll
    for (int tap = 0; tap < KTAP; ++tap) {
      int s = tap * 8 + (c >> 5);
      abf2[((size_t)(s * 16 + rb) * 64 + lane) * 8 + j] = (unsigned short)f2bf(f[tap]);
    }
  }
}

// gather bank: 4 steps x 4 corners x 4 channels (uint2 = 8B each)
struct GBank { uint2 g[16]; f32x4 w; };

__device__ __forceinline__ f32x2 unpk(unsigned u) {
  return (f32x2){asf(u << 16), asf(u & 0xffff0000u)};
}

// bilinear combine of 4 channels from 4 corners -> 4 bf16 (8B) into LDS
__device__ __forceinline__ void build4(uint2 g0, uint2 g1, uint2 g2, uint2 g3,
                                       f32x4 w, char* dst) {
  f32x2 lo = w.x * unpk(g0.x) + w.y * unpk(g1.x) + w.z * unpk(g2.x) + w.w * unpk(g3.x);
  f32x2 hi = w.x * unpk(g0.y) + w.y * unpk(g1.y) + w.z * unpk(g2.y) + w.w * unpk(g3.y);
  unsigned o0, o1;
  asm("v_cvt_pk_bf16_f32 %0, %1, %2" : "=v"(o0) : "v"(lo.x), "v"(lo.y));
  asm("v_cvt_pk_bf16_f32 %0, %1, %2" : "=v"(o1) : "v"(hi.x), "v"(hi.y));
  *(uint2*)dst = make_uint2(o0, o1);
}

#define MFMA_BF16 __builtin_amdgcn_mfma_f32_16x16x32_bf16

// One phase = 4 K-steps. PAR is a literal (P&1).
// Consumers: read buf[PAR] (16 ds_read_b128), load A (8 dwordx4), 32 MFMA.
// Producers: issue 16 gathers for phase P+2 into BN; build phase P+1 from BC
// into buf[PAR^1]; lgkmcnt(0). One barrier per phase.
#define PHASE(P, PAR, BC, BN)                                                  \
  do {                                                                         \
    if (cons) {                                                                \
      const char* bb_ = (const char*)&Bl[0][0][0] + (PAR) * 16384;             \
      _Pragma("unroll")                                                        \
      for (int j = 0; j < 4; ++j) {                                            \
        const char* ap_ = aoff0 + (size_t)(4 * (P) + j) * A_PLANE;             \
        bf16x8 a0_ = *(const bf16x8*)(ap_);                                    \
        bf16x8 a1_ = *(const bf16x8*)(ap_ + 1024);                             \
        bf16x8 b0_ = *(const bf16x8*)(bb_ + j * 4096 + bo0);                   \
        bf16x8 b1_ = *(const bf16x8*)(bb_ + j * 4096 + bo1);                   \
        bf16x8 b2_ = *(const bf16x8*)(bb_ + j * 4096 + bo2);                   \
        bf16x8 b3_ = *(const bf16x8*)(bb_ + j * 4096 + bo3);                   \
        __builtin_amdgcn_s_setprio(1);                                         \
        acc[0][0] = MFMA_BF16(a0_, b0_, acc[0][0], 0, 0, 0);                   \
        acc[1][0] = MFMA_BF16(a1_, b0_, acc[1][0], 0, 0, 0);                   \
        acc[0][1] = MFMA_BF16(a0_, b1_, acc[0][1], 0, 0, 0);                   \
        acc[1][1] = MFMA_BF16(a1_, b1_, acc[1][1], 0, 0, 0);                   \
        acc[0][2] = MFMA_BF16(a0_, b2_, acc[0][2], 0, 0, 0);                   \
        acc[1][2] = MFMA_BF16(a1_, b2_, acc[1][2], 0, 0, 0);                   \
        acc[0][3] = MFMA_BF16(a0_, b3_, acc[0][3], 0, 0, 0);                   \
        acc[1][3] = MFMA_BF16(a1_, b3_, acc[1][3], 0, 0, 0);                   \
        __builtin_amdgcn_s_setprio(0);                                         \
      }                                                                        \
    } else {                                                                   \
      int q2_ = (P) + 2 < NPH ? (P) + 2 : NPH - 1;                             \
      int tq_ = q2_ >> 1;                                                      \
      uint4 ra_ = *(const uint4*)&recA[(tq_ * 64 + px) * 4];                   \
      BN.w = *(const f32x4*)&recW[(tq_ * 64 + px) * 4];                        \
      unsigned cq_ = (unsigned)((q2_ & 1) * 256) + kg8;                        \
      _Pragma("unroll")                                                        \
      for (int j = 0; j < 4; ++j) {                                            \
        BN.g[j * 4 + 0] = *(const uint2*)(nb_u + ra_.x + cq_ + j * 64);        \
        BN.g[j * 4 + 1] = *(const uint2*)(nb_u + ra_.y + cq_ + j * 64);        \
        BN.g[j * 4 + 2] = *(const uint2*)(nb_u + ra_.z + cq_ + j * 64);        \
        BN.g[j * 4 + 3] = *(const uint2*)(nb_u + ra_.w + cq_ + j * 64);        \
      }                                                                        \
      __builtin_amdgcn_sched_barrier(0);                                       \
      char* wb_ = (char*)&Bl[0][0][0] + ((PAR) ^ 1) * 16384 + pwoff;           \
      _Pragma("unroll")                                                        \
      for (int j = 0; j < 4; ++j)                                              \
        build4(BC.g[j * 4 + 0], BC.g[j * 4 + 1], BC.g[j * 4 + 2],              \
               BC.g[j * 4 + 3], BC.w, wb_ + j * 4096);                         \
      asm volatile("s_waitcnt lgkmcnt(0)" ::: "memory");                       \
    }                                                                          \
    __builtin_amdgcn_s_barrier();                                              \
  } while (0)

// ---------------- fused sample + GEMM (4-step phases, 18 barriers) -----------
// 256 blocks x 1024 threads (16 waves):
//   waves 0-7  = consumers: wave tile 32 Cout x 64 px, 32 MFMA/phase
//   waves 8-15 = producers: 512 thr = (px 0..63, kg 0..7), 4 ch each
// B LDS: 2 phase-buffers x 4 steps x 4KB; per step plane p=ch>>3 (0..3):
//   addr = p*1024 + ((px+5p)&63)*16  (+8 for kg odd) — bank-clean b64/b128.
__global__ __launch_bounds__(1024, 4) void k_dcn_gemm(const unsigned short* __restrict__ nhwc,
                                                      const unsigned short* __restrict__ abf2,
                                                      const float* __restrict__ offs,
                                                      const float* __restrict__ msk,
                                                      float* __restrict__ out) {
  __shared__ __align__(16) unsigned short Bl[2][4][2048];  // 32KB
  __shared__ float recW[KTAP * 64 * 4];
  __shared__ unsigned recA[KTAP * 64 * 4];

  int bid = blockIdx.x;
  int b = ((bid & 7) << 5) | (bid >> 3);  // XCD-aware swizzle (bijective)
  int n = b >> 6;
  int ho = b & 63;
  int hw0 = ho << 6;
  int t = threadIdx.x;

  // --- per (pixel, tap) sampling records ---
  if (t < 576) {
    int r = t;
    int pl = r / 9;
    int tap = r - pl * 9;
    int hw = hw0 + pl;
    float dy = offs[(size_t)(n * 18 + 2 * tap) * HW_ + hw];
    float dx = offs[(size_t)(n * 18 + 2 * tap + 1) * HW_ + hw];
    float mk = msk[(size_t)(n * 9 + tap) * HW_ + hw];
    float y = (float)(ho - 1 + tap / 3) + dy;
    float x = (float)(pl - 1 + tap % 3) + dx;
    float fy = floorf(y), fx = floorf(x);
    float ly = y - fy, lx = x - fx;
    int y0 = (int)fy, x0 = (int)fx;
    int y1 = y0 + 1, x1 = x0 + 1;
    float vy0 = (y0 >= 0 && y0 < 64) ? 1.f : 0.f;
    float vy1 = (y1 >= 0 && y1 < 64) ? 1.f : 0.f;
    float vx0 = (x0 >= 0 && x0 < 64) ? 1.f : 0.f;
    float vx1 = (x1 >= 0 && x1 < 64) ? 1.f : 0.f;
    int y0c = min(max(y0, 0), 63), y1c = min(max(y1, 0), 63);
    int x0c = min(max(x0, 0), 63), x1c = min(max(x1, 0), 63);
    int base = (tap * 64 + pl) * 4;
    recW[base + 0] = (1.f - ly) * (1.f - lx) * mk * vy0 * vx0;
    recW[base + 1] = (1.f - ly) * lx * mk * vy0 * vx1;
    recW[base + 2] = ly * (1.f - lx) * mk * vy1 * vx0;
    recW[base + 3] = ly * lx * mk * vy1 * vx1;
    recA[base + 0] = (unsigned)((y0c * 64 + x0c) * 512);
    recA[base + 1] = (unsigned)((y0c * 64 + x1c) * 512);
    recA[base + 2] = (unsigned)((y1c * 64 + x0c) * 512);
    recA[base + 3] = (unsigned)((y1c * 64 + x1c) * 512);
  }
  __syncthreads();

  int lane = t & 63, wv = t >> 6;
  bool cons = wv < 8;

  // consumer addressing: wave wv owns Cout [wv*32, wv*32+32)
  const char* aoff0 = (const char*)abf2 + ((wv * 2 + 0) * 64 + lane) * 16;
  int p_r = lane >> 4;
  int pxl = lane & 15;
  const int bo0 = p_r * 1024 + (((pxl + 0) + 5 * p_r) & 63) * 16;
  const int bo1 = p_r * 1024 + (((pxl + 16) + 5 * p_r) & 63) * 16;
  const int bo2 = p_r * 1024 + (((pxl + 32) + 5 * p_r) & 63) * 16;
  const int bo3 = p_r * 1024 + (((pxl + 48) + 5 * p_r) & 63) * 16;

  // producer addressing (threads 512..1023): (px 0..63, kg 0..7), 4 ch each
  int pid = t - 512;
  int px = (pid >> 3) & 63;
  int kg = pid & 7;
  unsigned kg8 = (unsigned)(kg * 8);
  const char* nb_u = (const char*)nhwc + (size_t)n * HW_ * C_ * 2;
  const int pwoff = (kg >> 1) * 1024 + ((px + 5 * (kg >> 1)) & 63) * 16 + (kg & 1) * 8;

  f32x4 acc[2][4];
#pragma unroll
  for (int mi = 0; mi < 2; ++mi)
#pragma unroll
    for (int ni = 0; ni < 4; ++ni) acc[mi][ni] = (f32x4){0.f, 0.f, 0.f, 0.f};

  GBank bkA, bkB;  // bkA: even-phase gathers, bkB: odd-phase gathers

  // --- prologue (producers): phase-0 gathers -> build buf0; phase-1 -> bkB ---
  if (!cons) {
    uint4 ra0 = *(const uint4*)&recA[px * 4];  // tap 0
    f32x4 w0 = *(const f32x4*)&recW[px * 4];
    bkA.w = w0;
    bkB.w = w0;
#pragma unroll
    for (int j = 0; j < 4; ++j) {
      bkA.g[j * 4 + 0] = *(const uint2*)(nb_u + ra0.x + kg8 + j * 64);
      bkA.g[j * 4 + 1] = *(const uint2*)(nb_u + ra0.y + kg8 + j * 64);
      bkA.g[j * 4 + 2] = *(const uint2*)(nb_u + ra0.z + kg8 + j * 64);
      bkA.g[j * 4 + 3] = *(const uint2*)(nb_u + ra0.w + kg8 + j * 64);
    }
#pragma unroll
    for (int j = 0; j < 4; ++j) {
      bkB.g[j * 4 + 0] = *(const uint2*)(nb_u + ra0.x + kg8 + 256 + j * 64);
      bkB.g[j * 4 + 1] = *(const uint2*)(nb_u + ra0.y + kg8 + 256 + j * 64);
      bkB.g[j * 4 + 2] = *(const uint2*)(nb_u + ra0.z + kg8 + 256 + j * 64);
      bkB.g[j * 4 + 3] = *(const uint2*)(nb_u + ra0.w + kg8 + 256 + j * 64);
    }
    char* wb = (char*)&Bl[0][0][0] + pwoff;
#pragma unroll
    for (int j = 0; j < 4; ++j)
      build4(bkA.g[j * 4 + 0], bkA.g[j * 4 + 1], bkA.g[j * 4 + 2],
             bkA.g[j * 4 + 3], bkA.w, wb + j * 4096);
    asm volatile("s_waitcnt lgkmcnt(0)" ::: "memory");
  }
  __builtin_amdgcn_s_barrier();

  // --- main loop: 18 phases (9 x 2, literal parity) ---
  for (int p2 = 0; p2 < NPH; p2 += 2) {
    PHASE(p2,     0, bkB, bkA);  // consume bkB (odd gathers), refill bkA
    PHASE(p2 + 1, 1, bkA, bkB);  // consume bkA (even gathers), refill bkB
  }

  // --- epilogue (consumers only): D row = Cout, col = px ---
  if (cons) {
    float* ob = out + (size_t)n * CO_ * HW_ + hw0;
#pragma unroll
    for (int mi = 0; mi < 2; ++mi)
#pragma unroll
      for (int ni = 0; ni < 4; ++ni)
#pragma unroll
        for (int jj = 0; jj < 4; ++jj) {
          int o = wv * 32 + mi * 16 + (lane >> 4) * 4 + jj;
          int hw = ni * 16 + (lane & 15);
          ob[(size_t)o * HW_ + hw] = acc[mi][ni][jj];
        }
  }
}

extern "C" void kernel_launch(void* const* d_in, const int* in_sizes, int n_in,
                              void* d_out, int out_size, void* d_ws, size_t ws_size,
                              hipStream_t stream) {
  const float* inp  = (const float*)d_in[0];
  const float* filt = (const float*)d_in[1];
  const float* offs = (const float*)d_in[2];
  const float* msk  = (const float*)d_in[3];
  float* out = (float*)d_out;
  if (ws_size < ABF_OFF + ABF_BYTES) return;  // ~9.6 MB scratch
  unsigned short* nhwc = (unsigned short*)d_ws;
  unsigned short* abf2 = (unsigned short*)((char*)d_ws + ABF_OFF);

  k_prep<<<1280, 256, 0, stream>>>(inp, filt, nhwc, abf2);
  k_dcn_gemm<<<256, 1024, 0, stream>>>(nhwc, abf2, offs, msk, out);
}

// Round 11
// 68.084 us; speedup vs baseline: 3.1899x; 1.0932x over previous
//
#include <hip/hip_runtime.h>
#include <stdint.h>

#define AS1 __attribute__((address_space(1)))
#define AS3 __attribute__((address_space(3)))

typedef __attribute__((ext_vector_type(2))) float f32x2;
typedef __attribute__((ext_vector_type(4))) float f32x4;
typedef __attribute__((ext_vector_type(8))) short bf16x8;

static constexpr int N_ = 4, C_ = 256, HW_ = 4096;
static constexpr int CO_ = 256, KTAP = 9;
static constexpr int NSTEP = 72;                   // K-steps of 32
static constexpr int A_PLANE = 16 * 64 * 16;       // one BK=32 plane of A: 16KB
static constexpr size_t TILE_STRIDE = 256 * 4096;  // Bglob: per-s stride (1MB)

static constexpr size_t NHWC_BYTES = (size_t)N_ * HW_ * C_ * 2;     // 8 MB
static constexpr size_t ABF_OFF    = NHWC_BYTES;
static constexpr size_t ABF_BYTES  = (size_t)NSTEP * A_PLANE;       // 1.18 MB
static constexpr size_t BG_OFF     = ABF_OFF + ABF_BYTES;
static constexpr size_t BG_BYTES   = (size_t)NSTEP * TILE_STRIDE;   // 75.5 MB

__device__ inline unsigned f2bf(float f) {
  unsigned u = __builtin_bit_cast(unsigned, f);
  unsigned r = u + 0x7FFFu + ((u >> 16) & 1u);
  return r >> 16;
}
__device__ inline float asf(unsigned u) { return __builtin_bit_cast(float, u); }

// ---------------- merged prep: NCHW->NHWC bf16 + filter->fragment-major ------
__global__ __launch_bounds__(256) void k_prep(const float* __restrict__ in,
                                              const float* __restrict__ filt,
                                              unsigned short* __restrict__ nhwc,
                                              unsigned short* __restrict__ abf2) {
  int b = blockIdx.x;
  int t = threadIdx.x;
  if (b < 1024) {
    __shared__ float tile[64][65];
    int n = b >> 8, cg = (b >> 6) & 3, hwg = b & 63;
    int c0 = cg * 64, hw0 = hwg * 64;
    int col = t & 63, r0 = t >> 6;
#pragma unroll
    for (int i = 0; i < 16; ++i) {
      int row = r0 + i * 4;
      tile[row][col] = in[(size_t)(n * C_ + c0 + row) * HW_ + hw0 + col];
    }
    __syncthreads();
    int pr = t >> 2, cc0 = (t & 3) * 16;
    unsigned us[8];
#pragma unroll
    for (int i = 0; i < 8; ++i) {
      unsigned lo = f2bf(tile[cc0 + 2 * i][pr]);
      unsigned hi = f2bf(tile[cc0 + 2 * i + 1][pr]);
      us[i] = lo | (hi << 16);
    }
    unsigned* dst = (unsigned*)(nhwc + (size_t)(n * HW_ + hw0 + pr) * C_ + c0 + cc0);
    ((uint4*)dst)[0] = make_uint4(us[0], us[1], us[2], us[3]);
    ((uint4*)dst)[1] = make_uint4(us[4], us[5], us[6], us[7]);
  } else {
    // abf2[((s*16 + rb)*64 + lane)*8 + j]: s = tap*8+(c>>5), rb=o>>4,
    // lane = ((c>>3)&3)*16 + (o&15), j = c&7.
    int gid = (b - 1024) * 256 + t;
    int o = gid >> 8, c = gid & 255;
    const float* f = filt + (size_t)(o * C_ + c) * KTAP;
    int rb = o >> 4;
    int lane = ((c >> 3) & 3) * 16 + (o & 15);
    int j = c & 7;
#pragma unroll
    for (int tap = 0; tap < KTAP; ++tap) {
      int s = tap * 8 + (c >> 5);
      abf2[((size_t)(s * 16 + rb) * 64 + lane) * 8 + j] = (unsigned short)f2bf(f[tap]);
    }
  }
}

__device__ __forceinline__ f32x2 unpk(unsigned u) {
  return (f32x2){asf(u << 16), asf(u & 0xffff0000u)};
}

// bilinear combine: 8 channels (one uint4 per corner) -> 16B (8 bf16)
__device__ __forceinline__ uint4 comb8(const uint4& g0, const uint4& g1,
                                       const uint4& g2, const uint4& g3, f32x4 w) {
  f32x2 r0 = w.x * unpk(g0.x) + w.y * unpk(g1.x) + w.z * unpk(g2.x) + w.w * unpk(g3.x);
  f32x2 r1 = w.x * unpk(g0.y) + w.y * unpk(g1.y) + w.z * unpk(g2.y) + w.w * unpk(g3.y);
  f32x2 r2 = w.x * unpk(g0.z) + w.y * unpk(g1.z) + w.z * unpk(g2.z) + w.w * unpk(g3.z);
  f32x2 r3 = w.x * unpk(g0.w) + w.y * unpk(g1.w) + w.z * unpk(g2.w) + w.w * unpk(g3.w);
  unsigned o0, o1, o2, o3;
  asm("v_cvt_pk_bf16_f32 %0, %1, %2" : "=v"(o0) : "v"(r0.x), "v"(r0.y));
  asm("v_cvt_pk_bf16_f32 %0, %1, %2" : "=v"(o1) : "v"(r1.x), "v"(r1.y));
  asm("v_cvt_pk_bf16_f32 %0, %1, %2" : "=v"(o2) : "v"(r2.x), "v"(r2.y));
  asm("v_cvt_pk_bf16_f32 %0, %1, %2" : "=v"(o3) : "v"(r3.x), "v"(r3.y));
  return make_uint4(o0, o1, o2, o3);
}

// ---------------- sampler: build Bglob fragment tiles ------------------------
// 2304 blocks = (row 0..255) x (tap 0..8); 512 threads = (px 0..63, cq 0..7).
// Thread (px,cq) produces 4 x 16B chunks: for j=0..3, channels j*64+cq*8..+8,
// -> tile s = tap*8 + j*2 + (cq>>2), row, offset px*64 + (cq&3)*16.
// Gather lane-map: 8 cq lanes of one px read consecutive 16B -> ~16 lines/instr.
__global__ __launch_bounds__(512, 2) void k_sample(const unsigned short* __restrict__ nhwc,
                                                   const float* __restrict__ offs,
                                                   const float* __restrict__ msk,
                                                   unsigned short* __restrict__ bglob) {
  __shared__ f32x4 sW[64];
  __shared__ uint4 sA[64];
  int bid = blockIdx.x;
  int b = (bid & 7) * 288 + (bid >> 3);  // XCD swizzle (2304 % 8 == 0)
  int row = b / 9, tap = b - row * 9;
  int n = row >> 6, ho = row & 63;
  int t = threadIdx.x;

  if (t < 64) {
    int pl = t, hw = ho * 64 + pl;
    float dy = offs[(size_t)(n * 18 + 2 * tap) * HW_ + hw];
    float dx = offs[(size_t)(n * 18 + 2 * tap + 1) * HW_ + hw];
    float mk = msk[(size_t)(n * 9 + tap) * HW_ + hw];
    float y = (float)(ho - 1 + tap / 3) + dy;
    float x = (float)(pl - 1 + tap % 3) + dx;
    float fy = floorf(y), fx = floorf(x);
    float ly = y - fy, lx = x - fx;
    int y0 = (int)fy, x0 = (int)fx;
    int y1 = y0 + 1, x1 = x0 + 1;
    float vy0 = (y0 >= 0 && y0 < 64) ? 1.f : 0.f;
    float vy1 = (y1 >= 0 && y1 < 64) ? 1.f : 0.f;
    float vx0 = (x0 >= 0 && x0 < 64) ? 1.f : 0.f;
    float vx1 = (x1 >= 0 && x1 < 64) ? 1.f : 0.f;
    int y0c = min(max(y0, 0), 63), y1c = min(max(y1, 0), 63);
    int x0c = min(max(x0, 0), 63), x1c = min(max(x1, 0), 63);
    sW[pl] = (f32x4){(1.f - ly) * (1.f - lx) * mk * vy0 * vx0,
                     (1.f - ly) * lx * mk * vy0 * vx1,
                     ly * (1.f - lx) * mk * vy1 * vx0,
                     ly * lx * mk * vy1 * vx1};
    sA[pl] = make_uint4((unsigned)((y0c * 64 + x0c) * 512),
                        (unsigned)((y0c * 64 + x1c) * 512),
                        (unsigned)((y1c * 64 + x0c) * 512),
                        (unsigned)((y1c * 64 + x1c) * 512));
  }
  __syncthreads();

  int px = t >> 3, cq = t & 7;
  f32x4 w = sW[px];
  uint4 ra = sA[px];
  const char* nb = (const char*)nhwc + (size_t)n * HW_ * C_ * 2;
  unsigned c16 = (unsigned)(cq * 16);

  uint4 g0[4], g1[4], g2[4], g3[4];
#pragma unroll
  for (int j = 0; j < 4; ++j) {
    unsigned o_ = (unsigned)(j * 128) + c16;
    g0[j] = *(const uint4*)(nb + ra.x + o_);
    g1[j] = *(const uint4*)(nb + ra.y + o_);
    g2[j] = *(const uint4*)(nb + ra.z + o_);
    g3[j] = *(const uint4*)(nb + ra.w + o_);
  }

  char* outb = (char*)bglob + (size_t)row * 4096 + px * 64 + (cq & 3) * 16;
  int sbase = tap * 8 + (cq >> 2);
#pragma unroll
  for (int j = 0; j < 4; ++j) {
    uint4 o4 = comb8(g0[j], g1[j], g2[j], g3[j], w);
    *(uint4*)(outb + (size_t)(sbase + j * 2) * TILE_STRIDE) = o4;
  }
}

#define MFMA_BF16 __builtin_amdgcn_mfma_f32_16x16x32_bf16

// One K-step of the streaming GEMM. P = literal LDS parity for B(S).
#define GSTEP(S, P)                                                            \
  do {                                                                         \
    int s1_ = (S) + 1 < NSTEP ? (S) + 1 : NSTEP - 1;                           \
    if (wv < 4) {                                                              \
      const char* src_ = bg + (size_t)s1_ * TILE_STRIDE + wv * 1024 + lane * 16; \
      __builtin_amdgcn_global_load_lds((const AS1 void*)src_,                  \
          (AS3 void*)((char*)&Bl[0][0] + ((P) ^ 1) * 4096 + wv * 1024 + lane * 16), \
          16, 0, 0);                                                           \
    }                                                                          \
    afn = *(const bf16x8*)(aoff + (size_t)s1_ * A_PLANE);                      \
    {                                                                          \
      const char* bb_ = (const char*)&Bl[0][0] + (P) * 4096;                   \
      bf16x8 b0_ = *(const bf16x8*)(bb_ + bo0);                                \
      bf16x8 b1_ = *(const bf16x8*)(bb_ + bo1);                                \
      bf16x8 b2_ = *(const bf16x8*)(bb_ + bo2);                                \
      bf16x8 b3_ = *(const bf16x8*)(bb_ + bo3);                                \
      __builtin_amdgcn_s_setprio(1);                                           \
      acc[0] = MFMA_BF16(afc, b0_, acc[0], 0, 0, 0);                           \
      acc[1] = MFMA_BF16(afc, b1_, acc[1], 0, 0, 0);                           \
      acc[2] = MFMA_BF16(afc, b2_, acc[2], 0, 0, 0);                           \
      acc[3] = MFMA_BF16(afc, b3_, acc[3], 0, 0, 0);                           \
      __builtin_amdgcn_s_setprio(0);                                           \
    }                                                                          \
    __syncthreads();                                                           \
    afc = afn;                                                                 \
  } while (0)

// ---------------- streaming GEMM: 256 blocks x 1024 thr (16 waves) -----------
// wave wv = Cout [wv*16, wv*16+16); A direct loads (contiguous 1KB/wave/step);
// B via global_load_lds (4KB/step, waves 0-3), double-buffered LDS.
__global__ __launch_bounds__(1024, 4) void k_gemm2(const unsigned short* __restrict__ bglob,
                                                   const unsigned short* __restrict__ abf2,
                                                   float* __restrict__ out) {
  __shared__ __align__(16) unsigned short Bl[2][2048];  // 2 x 4KB
  int bid = blockIdx.x;
  int b = ((bid & 7) << 5) | (bid >> 3);  // XCD swizzle
  int n = b >> 6, ho = b & 63, hw0 = ho << 6;
  int t = threadIdx.x, lane = t & 63, wv = t >> 6;

  const char* aoff = (const char*)abf2 + ((size_t)(wv * 64 + lane)) * 16;
  const char* bg = (const char*)bglob + (size_t)b * 4096;
  int pxl = lane & 15, kq = lane >> 4;
  const int bo0 = 0 * 1024 + pxl * 64 + kq * 16;
  const int bo1 = 1 * 1024 + pxl * 64 + kq * 16;
  const int bo2 = 2 * 1024 + pxl * 64 + kq * 16;
  const int bo3 = 3 * 1024 + pxl * 64 + kq * 16;

  f32x4 acc[4];
#pragma unroll
  for (int ni = 0; ni < 4; ++ni) acc[ni] = (f32x4){0.f, 0.f, 0.f, 0.f};

  bf16x8 afc, afn;
  // prologue: stage B(0) into buf0, load A(0)
  if (wv < 4) {
    const char* src = bg + wv * 1024 + lane * 16;
    __builtin_amdgcn_global_load_lds((const AS1 void*)src,
        (AS3 void*)((char*)&Bl[0][0] + wv * 1024 + lane * 16), 16, 0, 0);
  }
  afc = *(const bf16x8*)(aoff);
  __syncthreads();

  for (int s = 0; s < NSTEP; s += 2) {
    GSTEP(s, 0);
    GSTEP(s + 1, 1);
  }

  float* ob = out + (size_t)n * CO_ * HW_ + hw0;
#pragma unroll
  for (int ni = 0; ni < 4; ++ni)
#pragma unroll
    for (int jj = 0; jj < 4; ++jj) {
      int o = wv * 16 + kq * 4 + jj;
      int hw = ni * 16 + pxl;
      ob[(size_t)o * HW_ + hw] = acc[ni][jj];
    }
}

// ---------------- fallback fused kernel (round-6 structure, race-fixed) ------
struct GB { uint4 g[4]; f32x4 w; };

#define FPIPE(S, RDP, WRP, GCON, GISS, AC0, AC1, AN0, AN1)                     \
  do {                                                                         \
    if (cons) {                                                                \
      int s1_ = (S) + 1 < NSTEP ? (S) + 1 : NSTEP - 1;                         \
      AN0 = *(const bf16x8*)(faoff0 + (size_t)s1_ * A_PLANE);                  \
      AN1 = *(const bf16x8*)(faoff0 + 1024 + (size_t)s1_ * A_PLANE);           \
      const char* bb_ = (const char*)&Bl[0][0] + (RDP) * 4096;                 \
      bf16x8 b0_ = *(const bf16x8*)(bb_ + fbo0);                               \
      bf16x8 b1_ = *(const bf16x8*)(bb_ + fbo1);                               \
      bf16x8 b2_ = *(const bf16x8*)(bb_ + fbo2);                               \
      bf16x8 b3_ = *(const bf16x8*)(bb_ + fbo3);                               \
      __builtin_amdgcn_s_setprio(1);                                           \
      acc[0][0] = MFMA_BF16(AC0, b0_, acc[0][0], 0, 0, 0);                     \
      acc[1][0] = MFMA_BF16(AC1, b0_, acc[1][0], 0, 0, 0);                     \
      acc[0][1] = MFMA_BF16(AC0, b1_, acc[0][1], 0, 0, 0);                     \
      acc[1][1] = MFMA_BF16(AC1, b1_, acc[1][1], 0, 0, 0);                     \
      acc[0][2] = MFMA_BF16(AC0, b2_, acc[0][2], 0, 0, 0);                     \
      acc[1][2] = MFMA_BF16(AC1, b2_, acc[1][2], 0, 0, 0);                     \
      acc[0][3] = MFMA_BF16(AC0, b3_, acc[0][3], 0, 0, 0);                     \
      acc[1][3] = MFMA_BF16(AC1, b3_, acc[1][3], 0, 0, 0);                     \
      __builtin_amdgcn_s_setprio(0);                                           \
    } else {                                                                   \
      int s2_ = (S) + 2 < NSTEP ? (S) + 2 : NSTEP - 1;                         \
      if ((s2_ & 7) == 0) {                                                    \
        int tp_ = s2_ >> 3;                                                    \
        uint4 ra_ = *(const uint4*)&recA[(tp_ * 64 + p_b) * 4];                \
        wS = *(const f32x4*)&recW[(tp_ * 64 + p_b) * 4];                       \
        vS.x = ra_.x + kq16; vS.y = ra_.y + kq16;                              \
        vS.z = ra_.z + kq16; vS.w = ra_.w + kq16;                              \
      }                                                                        \
      unsigned co_ = (unsigned)((s2_ & 7) * 64);                               \
      GISS.g[0] = *(const uint4*)(nb_u + vS.x + co_);                          \
      GISS.g[1] = *(const uint4*)(nb_u + vS.y + co_);                          \
      GISS.g[2] = *(const uint4*)(nb_u + vS.z + co_);                          \
      GISS.g[3] = *(const uint4*)(nb_u + vS.w + co_);                          \
      GISS.w = wS;                                                             \
      uint4 o4_ = comb8(GCON.g[0], GCON.g[1], GCON.g[2], GCON.g[3], GCON.w);   \
      *(uint4*)(bwp + (WRP) * 4096) = o4_;                                     \
      asm volatile("s_waitcnt lgkmcnt(0)" ::: "memory");                       \
    }                                                                          \
    asm volatile("" ::: "memory");                                             \
    __builtin_amdgcn_s_barrier();                                              \
    asm volatile("" ::: "memory");                                             \
  } while (0)

__global__ __launch_bounds__(768, 3) void k_fused(const unsigned short* __restrict__ nhwc,
                                                  const unsigned short* __restrict__ abf2,
                                                  const float* __restrict__ offs,
                                                  const float* __restrict__ msk,
                                                  float* __restrict__ out) {
  __shared__ __align__(16) unsigned short Bl[2][2048];
  __shared__ float recW[KTAP * 64 * 4];
  __shared__ unsigned recA[KTAP * 64 * 4];

  int bid = blockIdx.x;
  int b = ((bid & 7) << 5) | (bid >> 3);
  int n = b >> 6, ho = b & 63, hw0 = ho << 6;
  int t = threadIdx.x;

  for (int r = t; r < 576; r += 768) {
    int pl = r / 9;
    int tap = r - pl * 9;
    int hw = hw0 + pl;
    float dy = offs[(size_t)(n * 18 + 2 * tap) * HW_ + hw];
    float dx = offs[(size_t)(n * 18 + 2 * tap + 1) * HW_ + hw];
    float mk = msk[(size_t)(n * 9 + tap) * HW_ + hw];
    float y = (float)(ho - 1 + tap / 3) + dy;
    float x = (float)(pl - 1 + tap % 3) + dx;
    float fy = floorf(y), fx = floorf(x);
    float ly = y - fy, lx = x - fx;
    int y0 = (int)fy, x0 = (int)fx;
    int y1 = y0 + 1, x1 = x0 + 1;
    float vy0 = (y0 >= 0 && y0 < 64) ? 1.f : 0.f;
    float vy1 = (y1 >= 0 && y1 < 64) ? 1.f : 0.f;
    float vx0 = (x0 >= 0 && x0 < 64) ? 1.f : 0.f;
    float vx1 = (x1 >= 0 && x1 < 64) ? 1.f : 0.f;
    int y0c = min(max(y0, 0), 63), y1c = min(max(y1, 0), 63);
    int x0c = min(max(x0, 0), 63), x1c = min(max(x1, 0), 63);
    int base = (tap * 64 + pl) * 4;
    recW[base + 0] = (1.f - ly) * (1.f - lx) * mk * vy0 * vx0;
    recW[base + 1] = (1.f - ly) * lx * mk * vy0 * vx1;
    recW[base + 2] = ly * (1.f - lx) * mk * vy1 * vx0;
    recW[base + 3] = ly * lx * mk * vy1 * vx1;
    recA[base + 0] = (unsigned)((y0c * 64 + x0c) * 512);
    recA[base + 1] = (unsigned)((y0c * 64 + x1c) * 512);
    recA[base + 2] = (unsigned)((y1c * 64 + x0c) * 512);
    recA[base + 3] = (unsigned)((y1c * 64 + x1c) * 512);
  }
  __syncthreads();

  int lane = t & 63, wv = t >> 6;
  bool cons = wv < 8;

  const char* faoff0 = (const char*)abf2 + ((wv * 2) * 64 + lane) * 16;
  int p_r = lane >> 4, pxl = lane & 15;
  const int fbo0 = p_r * 1024 + (((pxl + 0) + 5 * p_r) & 63) * 16;
  const int fbo1 = p_r * 1024 + (((pxl + 16) + 5 * p_r) & 63) * 16;
  const int fbo2 = p_r * 1024 + (((pxl + 32) + 5 * p_r) & 63) * 16;
  const int fbo3 = p_r * 1024 + (((pxl + 48) + 5 * p_r) & 63) * 16;

  int pid = t - 512;
  int p_b = (pid >> 2) & 63;
  int kq = pid & 3;
  unsigned kq16 = (unsigned)(kq * 16);
  const char* nb_u = (const char*)nhwc + (size_t)n * HW_ * C_ * 2;
  char* bwp = (char*)&Bl[0][0] + kq * 1024 + ((p_b + 5 * kq) & 63) * 16;

  f32x4 acc[2][4];
#pragma unroll
  for (int mi = 0; mi < 2; ++mi)
#pragma unroll
    for (int ni = 0; ni < 4; ++ni) acc[mi][ni] = (f32x4){0.f, 0.f, 0.f, 0.f};

  GB gA, gB;
  bf16x8 afc0, afc1, afn0, afn1;
  uint4 vS;
  f32x4 wS;

  if (cons) {
    afc0 = *(const bf16x8*)(faoff0);
    afc1 = *(const bf16x8*)(faoff0 + 1024);
  } else {
    uint4 ra0 = *(const uint4*)&recA[p_b * 4];
    wS = *(const f32x4*)&recW[p_b * 4];
    vS.x = ra0.x + kq16; vS.y = ra0.y + kq16;
    vS.z = ra0.z + kq16; vS.w = ra0.w + kq16;
    gA.g[0] = *(const uint4*)(nb_u + vS.x);
    gA.g[1] = *(const uint4*)(nb_u + vS.y);
    gA.g[2] = *(const uint4*)(nb_u + vS.z);
    gA.g[3] = *(const uint4*)(nb_u + vS.w);
    gA.w = wS;
    gB.g[0] = *(const uint4*)(nb_u + vS.x + 64);
    gB.g[1] = *(const uint4*)(nb_u + vS.y + 64);
    gB.g[2] = *(const uint4*)(nb_u + vS.z + 64);
    gB.g[3] = *(const uint4*)(nb_u + vS.w + 64);
    gB.w = wS;
    uint4 o4 = comb8(gA.g[0], gA.g[1], gA.g[2], gA.g[3], gA.w);
    *(uint4*)(bwp) = o4;
    asm volatile("s_waitcnt lgkmcnt(0)" ::: "memory");
  }
  asm volatile("" ::: "memory");
  __builtin_amdgcn_s_barrier();
  asm volatile("" ::: "memory");

  for (int s = 0; s < NSTEP; s += 2) {
    FPIPE(s,     0, 1, gB, gA, afc0, afc1, afn0, afn1);
    FPIPE(s + 1, 1, 0, gA, gB, afn0, afn1, afc0, afc1);
  }

  if (cons) {
    float* ob = out + (size_t)n * CO_ * HW_ + hw0;
#pragma unroll
    for (int mi = 0; mi < 2; ++mi)
#pragma unroll
      for (int ni = 0; ni < 4; ++ni)
#pragma unroll
        for (int jj = 0; jj < 4; ++jj) {
          int o = wv * 32 + mi * 16 + (lane >> 4) * 4 + jj;
          int hw = ni * 16 + (lane & 15);
          ob[(size_t)o * HW_ + hw] = acc[mi][ni][jj];
        }
  }
}

extern "C" void kernel_launch(void* const* d_in, const int* in_sizes, int n_in,
                              void* d_out, int out_size, void* d_ws, size_t ws_size,
                              hipStream_t stream) {
  const float* inp  = (const float*)d_in[0];
  const float* filt = (const float*)d_in[1];
  const float* offs = (const float*)d_in[2];
  const float* msk  = (const float*)d_in[3];
  float* out = (float*)d_out;
  if (ws_size < ABF_OFF + ABF_BYTES) return;
  unsigned short* nhwc = (unsigned short*)d_ws;
  unsigned short* abf2 = (unsigned short*)((char*)d_ws + ABF_OFF);

  k_prep<<<1280, 256, 0, stream>>>(inp, filt, nhwc, abf2);
  if (ws_size >= BG_OFF + BG_BYTES) {
    unsigned short* bglob = (unsigned short*)((char*)d_ws + BG_OFF);
    k_sample<<<2304, 512, 0, stream>>>(nhwc, offs, msk, bglob);
    k_gemm2<<<256, 1024, 0, stream>>>(bglob, abf2, out);
  } else {
    k_fused<<<256, 768, 0, stream>>>(nhwc, abf2, offs, msk, out);
  }
}